// Round 1
// baseline (352.774 us; speedup 1.0000x reference)
//
#include <hip/hip_runtime.h>
#include <math.h>

#define HH 2048
#define WW 2048
#define RAD 5
#define PITCH 43            // 42-wide halo rows, padded to odd pitch
#define PP (26*PITCH)       // per-field plane size (floats)

// ws layout (bytes):
// 0    : float gwin[11]     (normalized g)
// 64   : float gwin3[11]    (g/3, folded channel-average for V pass)
// 128  : double lG[4]
// 256  : double lYpart[1024]
// 8448 : double qpart[8192]

__device__ inline double wave_red(double v) {
#pragma unroll
  for (int o = 32; o > 0; o >>= 1) v += __shfl_down(v, o, 64);
  return v;
}

// coverage weight of input row/col r under zero-padded SAME conv (taps g[0..10])
__device__ inline float cov_w(int r, const float* g) {
  if (r >= RAD && r <= HH - 1 - RAD) return 1.0f;
  int dlo = r - (HH - 1 - RAD); if (dlo < 0) dlo = 0;   // max(0, r+5-(H-1))
  int dhi = r + RAD;            if (dhi > 10) dhi = 10;
  float s = 0.0f;
  for (int d = dlo; d <= dhi; ++d) s += g[d];
  return s;
}

__global__ void k0_window(float* gwin, float* gwin3) {
  if (threadIdx.x == 0) {
    double e[11], s = 0.0;
    double sig = 11.0 / 6.0;
    for (int i = 0; i < 11; ++i) {
      double x = (double)(i - 5);
      e[i] = exp(-(x * x) / (2.0 * sig * sig));
      s += e[i];
    }
    for (int i = 0; i < 11; ++i) {
      gwin[i]  = (float)(e[i] / s);
      gwin3[i] = (float)(e[i] / (3.0 * s));
    }
  }
}

// lY partial sums: Sum over Ys[k] of val * wy(y) * wx(x)  (channel-collapsed analytically)
__global__ __launch_bounds__(256) void k1_lY(const float* __restrict__ Ys,
                                             const float* __restrict__ gwin,
                                             double* __restrict__ lYpart) {
  int bid = blockIdx.x;
  int k = bid >> 8;          // 4 k-slices x 256 blocks
  int s = bid & 255;
  const float* Yk = Ys + (size_t)k * (3u * (size_t)HH * WW);
  float g[11];
#pragma unroll
  for (int i = 0; i < 11; ++i) g[i] = gwin[i];
  double acc = 0.0;
  int base = s * 49152;      // 12,582,912 / 256
  for (int i = base + (int)threadIdx.x; i < base + 49152; i += 256) {
    int rem = i & (HH * WW - 1);   // 2^22
    int y = rem >> 11;
    int x = rem & (WW - 1);
    float w = cov_w(y, g) * cov_w(x, g);
    acc += (double)Yk[i] * (double)w;
  }
  acc = wave_red(acc);
  __shared__ double red[4];
  int lane = threadIdx.x & 63, wid = threadIdx.x >> 6;
  if (lane == 0) red[wid] = acc;
  __syncthreads();
  if (threadIdx.x == 0) lYpart[bid] = red[0] + red[1] + red[2] + red[3];
}

__global__ __launch_bounds__(256) void k2a_lG(const double* __restrict__ lYpart,
                                              double* __restrict__ lG) {
  __shared__ double red[4];
  for (int k = 0; k < 4; ++k) {
    double v = lYpart[k * 256 + threadIdx.x];
    v = wave_red(v);
    int lane = threadIdx.x & 63, wid = threadIdx.x >> 6;
    if (lane == 0) red[wid] = v;
    __syncthreads();
    if (threadIdx.x == 0) {
      double tot = red[0] + red[1] + red[2] + red[3];
      double lY = tot * (1.0 / 12582912.0);   // /(3*H*W): includes window /3
      double d = lY - 0.5;
      lG[k] = exp(-(d * d) / 0.08);
    }
    __syncthreads();
  }
}

// Main fused pass: 32x16 output tile, 42x26 halo, 14 product fields,
// in-place separable blur in LDS, per-pixel fusion, block partial of l*cs.
__global__ __launch_bounds__(512) void k2_main(const float* __restrict__ X,
                                               const float* __restrict__ Ys,
                                               const float* __restrict__ gwin,
                                               const float* __restrict__ gwin3,
                                               const double* __restrict__ lG,
                                               double* __restrict__ qpart) {
  __shared__ float prod[14 * PP];   // 62,608 B
  __shared__ double qred[8];

  int bid = blockIdx.x;
  // XCD-compact swizzle (8192 % 8 == 0, bijective): x-adjacent tiles share L2
  int wg = (bid & 7) * 1024 + (bid >> 3);
  int tX = wg & 63, tY = wg >> 6;     // 64 x-tiles, 128 y-tiles
  int x0 = tX * 32, y0 = tY * 16;
  int tid = threadIdx.x;

  float g[11], g3[11];
#pragma unroll
  for (int i = 0; i < 11; ++i) { g[i] = gwin[i]; g3[i] = gwin3[i]; }

  // ---- Stage A: channel-collapsed products into LDS planes (halo 42x26) ----
  const size_t PL = (size_t)HH * WW;
  for (int pos = tid; pos < 42 * 26; pos += 512) {
    int py = pos / 42;
    int px = pos - py * 42;
    int gy = y0 - RAD + py;
    int gx = x0 - RAD + px;
    float xv0 = 0.f, xv1 = 0.f, xv2 = 0.f;
    float yv[12];
#pragma unroll
    for (int j = 0; j < 12; ++j) yv[j] = 0.f;
    if ((unsigned)gy < (unsigned)HH && (unsigned)gx < (unsigned)WW) {
      size_t off = (size_t)gy * WW + gx;
      xv0 = X[off];
      xv1 = X[off + PL];
      xv2 = X[off + 2 * PL];
#pragma unroll
      for (int j = 0; j < 12; ++j) yv[j] = Ys[off + (size_t)j * PL];
    }
    int o = py * PITCH + px;
    prod[0 * PP + o] = xv0 + xv1 + xv2;
    prod[1 * PP + o] = xv0 * xv0 + xv1 * xv1 + xv2 * xv2;
#pragma unroll
    for (int k = 0; k < 4; ++k) {
      float a = yv[3 * k], b = yv[3 * k + 1], c = yv[3 * k + 2];
      prod[(2 + k) * PP + o]  = a + b + c;
      prod[(6 + k) * PP + o]  = a * a + b * b + c * c;
      prod[(10 + k) * PP + o] = xv0 * a + xv1 * b + xv2 * c;
    }
  }
  __syncthreads();

  // ---- Stage B: horizontal 11-tap blur, in place, register sliding window ----
  // tasks: 14 fields x 26 rows x 4 groups of 8 outputs = 1456; rows never cross
  // iteration boundaries (512 % 4 == 0), blur is within-row only.
#pragma unroll 1
  for (int it = 0; it < 3; ++it) {
    int t = it * 512 + tid;
    bool valid = t < 1456;
    int f = 0, py = 0, xg = 0;
    float w[18];
    if (valid) {
      f = t / 104;
      int rr = t - f * 104;
      py = rr >> 2;
      xg = (rr & 3) * 8;
      int base = f * PP + py * PITCH + xg;
#pragma unroll
      for (int j = 0; j < 18; ++j) w[j] = prod[base + j];
    }
    __syncthreads();
    if (valid) {
      int base = f * PP + py * PITCH + xg;
#pragma unroll
      for (int o = 0; o < 8; ++o) {
        float s = 0.f;
#pragma unroll
        for (int d = 0; d < 11; ++d) s += g[d] * w[o + d];
        prod[base + o] = s;
      }
    }
    __syncthreads();
  }

  // ---- Stage C: vertical 11-tap blur (taps include /3), thread-per-column ----
  if (tid < 448) {                 // 14 fields x 32 columns
    int f = tid >> 5, tx = tid & 31;
    int base = f * PP + tx;
    float col[26];
#pragma unroll
    for (int py = 0; py < 26; ++py) col[py] = prod[base + py * PITCH];
#pragma unroll
    for (int ty = 0; ty < 16; ++ty) {
      float s = 0.f;
#pragma unroll
      for (int d = 0; d < 11; ++d) s += g3[d] * col[ty + d];
      prod[base + ty * PITCH] = s;
    }
  }
  __syncthreads();

  // ---- Stage D: per-pixel fusion + block reduction ----
  {
    int ty = tid >> 5, tx = tid & 31;   // 512 threads = full 16x32 tile
    int o = ty * PITCH + tx;
    float b[14];
#pragma unroll
    for (int f = 0; f < 14; ++f) b[f] = prod[f * PP + o];
    float muX = b[0];
    float muX2 = muX * muX;
    float sigX = b[1] - muX2;
    float num = 0.f, den = 0.f;
    float best_sig = -1e30f, best_cs = 0.f;
#pragma unroll
    for (int k = 0; k < 4; ++k) {
      float muY  = b[2 + k];
      float sigY = b[6 + k] - muY * muY;
      float sXY  = b[10 + k] - muX * muY;
      float cs = (2.f * sXY + 9e-4f) / (sigX + sigY + 9e-4f);
      if (sigY > best_sig) { best_sig = sigY; best_cs = cs; }  // first-max wins
      float dm = muY - 0.5f;
      float lL = expf(-dm * dm * 12.5f);          // /DENOM_L = *12.5
      float LY = (float)lG[k] * lL;
      num += LY * muY;
      den += LY;
    }
    float muYw = num / den;
    float l = (2.f * muX * muYw + 1e-4f) / (muX2 + muYw * muYw + 1e-4f);
    double v = (double)(l * best_cs);
    v = wave_red(v);
    int lane = tid & 63, wid = tid >> 6;
    if (lane == 0) qred[wid] = v;
    __syncthreads();
    if (tid == 0) {
      double t = 0.0;
#pragma unroll
      for (int i = 0; i < 8; ++i) t += qred[i];
      qpart[blockIdx.x] = t;
    }
  }
}

__global__ __launch_bounds__(512) void k3_final(const double* __restrict__ qpart,
                                                float* __restrict__ out) {
  double acc = 0.0;
  for (int i = threadIdx.x; i < 8192; i += 512) acc += qpart[i];
  acc = wave_red(acc);
  __shared__ double red[8];
  int lane = threadIdx.x & 63, wid = threadIdx.x >> 6;
  if (lane == 0) red[wid] = acc;
  __syncthreads();
  if (threadIdx.x == 0) out[0] = (float)(acc = (red[0]+red[1]+red[2]+red[3]+red[4]+red[5]+red[6]+red[7]) * (1.0 / 4194304.0));
}

extern "C" void kernel_launch(void* const* d_in, const int* in_sizes, int n_in,
                              void* d_out, int out_size, void* d_ws, size_t ws_size,
                              hipStream_t stream) {
  const float* X  = (const float*)d_in[0];
  const float* Ys = (const float*)d_in[1];
  char* ws = (char*)d_ws;
  float*  gwin   = (float*)(ws + 0);
  float*  gwin3  = (float*)(ws + 64);
  double* lG     = (double*)(ws + 128);
  double* lYpart = (double*)(ws + 256);
  double* qpart  = (double*)(ws + 8448);
  float* out = (float*)d_out;

  hipLaunchKernelGGL(k0_window, dim3(1), dim3(64), 0, stream, gwin, gwin3);
  hipLaunchKernelGGL(k1_lY, dim3(1024), dim3(256), 0, stream, Ys, gwin, lYpart);
  hipLaunchKernelGGL(k2a_lG, dim3(1), dim3(256), 0, stream, lYpart, lG);
  hipLaunchKernelGGL(k2_main, dim3(8192), dim3(512), 0, stream, X, Ys, gwin, gwin3, lG, qpart);
  hipLaunchKernelGGL(k3_final, dim3(1), dim3(512), 0, stream, qpart, out);
}

// Round 2
// 266.769 us; speedup vs baseline: 1.3224x; 1.3224x over previous
//
#include <hip/hip_runtime.h>
#include <math.h>

#define HH 2048
#define WW 2048
#define RAD 5
#define PITCH 43            // 42-wide halo rows, padded to odd pitch
#define PP (26*PITCH)       // per-field plane size (floats)

// ws layout (bytes):
// 0     : float gwin[11]     (normalized g)
// 64    : float gwin3[11]    (g/3, folded channel-average for V pass)
// 128   : double lG[4]
// 256   : double lYpart[2048]   (16384 B)
// 16640 : double qpart[8192]    (65536 B)

__device__ inline double wave_red(double v) {
#pragma unroll
  for (int o = 32; o > 0; o >>= 1) v += __shfl_down(v, o, 64);
  return v;
}

// coverage weight of input row/col r under zero-padded SAME conv (taps g[0..10])
__device__ inline float cov_w(int r, const float* g) {
  if (r >= RAD && r <= HH - 1 - RAD) return 1.0f;
  int dlo = r - (HH - 1 - RAD); if (dlo < 0) dlo = 0;   // max(0, r+5-(H-1))
  int dhi = r + RAD;            if (dhi > 10) dhi = 10;
  float s = 0.0f;
  for (int d = dlo; d <= dhi; ++d) s += g[d];
  return s;
}

__global__ void k0_window(float* gwin, float* gwin3) {
  if (threadIdx.x == 0) {
    double e[11], s = 0.0;
    double sig = 11.0 / 6.0;
    for (int i = 0; i < 11; ++i) {
      double x = (double)(i - 5);
      e[i] = exp(-(x * x) / (2.0 * sig * sig));
      s += e[i];
    }
    for (int i = 0; i < 11; ++i) {
      gwin[i]  = (float)(e[i] / s);
      gwin3[i] = (float)(e[i] / (3.0 * s));
    }
  }
}

// lY partial sums: Sum over Ys[k] of val * wy(y) * wx(x), float4 streaming.
// 2048 blocks, 512 per k (512*6144 = 3*H*W/4 exactly -> k-aligned chunks).
__global__ __launch_bounds__(256) void k1_lY(const float4* __restrict__ Ys4,
                                             const float* __restrict__ gwin,
                                             double* __restrict__ lYpart) {
  int bid = blockIdx.x;
  float g[11];
#pragma unroll
  for (int i = 0; i < 11; ++i) g[i] = gwin[i];
  double acc = 0.0;
  int base = bid * 6144;
#pragma unroll 1
  for (int it = 0; it < 24; ++it) {
    int j = base + it * 256 + (int)threadIdx.x;
    float4 v = Ys4[j];
    int p4 = j & (1048576 - 1);      // pos within one HxW plane (in float4s)
    int y = p4 >> 9;                 // 512 float4s per row
    int xg = p4 & 511;
    float wy = (y >= RAD && y <= HH - 1 - RAD) ? 1.0f : cov_w(y, g);
    float s;
    if (xg >= 2 && xg < 510) {       // all 4 columns interior: wx == 1
      s = (v.x + v.y) + (v.z + v.w);
    } else {
      int x0 = xg << 2;
      s = v.x * cov_w(x0, g) + v.y * cov_w(x0 + 1, g)
        + v.z * cov_w(x0 + 2, g) + v.w * cov_w(x0 + 3, g);
    }
    acc += (double)(wy * s);
  }
  acc = wave_red(acc);
  __shared__ double red[4];
  int lane = threadIdx.x & 63, wid = threadIdx.x >> 6;
  if (lane == 0) red[wid] = acc;
  __syncthreads();
  if (threadIdx.x == 0) lYpart[bid] = red[0] + red[1] + red[2] + red[3];
}

__global__ __launch_bounds__(256) void k2a_lG(const double* __restrict__ lYpart,
                                              double* __restrict__ lG) {
  __shared__ double red[4];
  for (int k = 0; k < 4; ++k) {
    double v = lYpart[k * 512 + threadIdx.x] + lYpart[k * 512 + 256 + threadIdx.x];
    v = wave_red(v);
    int lane = threadIdx.x & 63, wid = threadIdx.x >> 6;
    if (lane == 0) red[wid] = v;
    __syncthreads();
    if (threadIdx.x == 0) {
      double tot = red[0] + red[1] + red[2] + red[3];
      double lY = tot * (1.0 / 12582912.0);   // /(3*H*W): includes window /3
      double d = lY - 0.5;
      lG[k] = exp(-(d * d) / 0.08);
    }
    __syncthreads();
  }
}

// Main fused pass: 32x16 output tile, 42x26 halo, 14 product fields,
// in-place separable blur in LDS, per-pixel fusion, block partial of l*cs.
__global__ __launch_bounds__(512) void k2_main(const float* __restrict__ X,
                                               const float* __restrict__ Ys,
                                               const float* __restrict__ gwin,
                                               const float* __restrict__ gwin3,
                                               const double* __restrict__ lG,
                                               double* __restrict__ qpart) {
  __shared__ float prod[14 * PP];   // 62,608 B
  __shared__ double qred[8];

  int bid = blockIdx.x;
  // XCD-compact swizzle (8192 % 8 == 0, bijective): x-adjacent tiles share L2
  int wg = (bid & 7) * 1024 + (bid >> 3);
  int tX = wg & 63, tY = wg >> 6;     // 64 x-tiles, 128 y-tiles
  int x0 = tX * 32, y0 = tY * 16;
  int tid = threadIdx.x;

  float g[11], g3[11];
#pragma unroll
  for (int i = 0; i < 11; ++i) { g[i] = gwin[i]; g3[i] = gwin3[i]; }

  // ---- Stage A: channel-collapsed products into LDS planes (halo 42x26) ----
  const size_t PL = (size_t)HH * WW;
  for (int pos = tid; pos < 42 * 26; pos += 512) {
    int py = pos / 42;
    int px = pos - py * 42;
    int gy = y0 - RAD + py;
    int gx = x0 - RAD + px;
    float xv0 = 0.f, xv1 = 0.f, xv2 = 0.f;
    float yv[12];
#pragma unroll
    for (int j = 0; j < 12; ++j) yv[j] = 0.f;
    if ((unsigned)gy < (unsigned)HH && (unsigned)gx < (unsigned)WW) {
      size_t off = (size_t)gy * WW + gx;
      xv0 = X[off];
      xv1 = X[off + PL];
      xv2 = X[off + 2 * PL];
#pragma unroll
      for (int j = 0; j < 12; ++j) yv[j] = Ys[off + (size_t)j * PL];
    }
    int o = py * PITCH + px;
    prod[0 * PP + o] = xv0 + xv1 + xv2;
    prod[1 * PP + o] = xv0 * xv0 + xv1 * xv1 + xv2 * xv2;
#pragma unroll
    for (int k = 0; k < 4; ++k) {
      float a = yv[3 * k], b = yv[3 * k + 1], c = yv[3 * k + 2];
      prod[(2 + k) * PP + o]  = a + b + c;
      prod[(6 + k) * PP + o]  = a * a + b * b + c * c;
      prod[(10 + k) * PP + o] = xv0 * a + xv1 * b + xv2 * c;
    }
  }
  __syncthreads();

  // ---- Stage B: horizontal 11-tap blur, in place, register sliding window ----
  // tasks: 14 fields x 26 rows x 4 groups of 8 outputs = 1456; rows never cross
  // iteration boundaries (512 % 4 == 0), blur is within-row only.
#pragma unroll 1
  for (int it = 0; it < 3; ++it) {
    int t = it * 512 + tid;
    bool valid = t < 1456;
    int f = 0, py = 0, xg = 0;
    float w[18];
    if (valid) {
      f = t / 104;
      int rr = t - f * 104;
      py = rr >> 2;
      xg = (rr & 3) * 8;
      int base = f * PP + py * PITCH + xg;
#pragma unroll
      for (int j = 0; j < 18; ++j) w[j] = prod[base + j];
    }
    __syncthreads();
    if (valid) {
      int base = f * PP + py * PITCH + xg;
#pragma unroll
      for (int o = 0; o < 8; ++o) {
        float s = 0.f;
#pragma unroll
        for (int d = 0; d < 11; ++d) s += g[d] * w[o + d];
        prod[base + o] = s;
      }
    }
    __syncthreads();
  }

  // ---- Stage C: vertical 11-tap blur (taps include /3), thread-per-column ----
  if (tid < 448) {                 // 14 fields x 32 columns
    int f = tid >> 5, tx = tid & 31;
    int base = f * PP + tx;
    float col[26];
#pragma unroll
    for (int py = 0; py < 26; ++py) col[py] = prod[base + py * PITCH];
#pragma unroll
    for (int ty = 0; ty < 16; ++ty) {
      float s = 0.f;
#pragma unroll
      for (int d = 0; d < 11; ++d) s += g3[d] * col[ty + d];
      prod[base + ty * PITCH] = s;
    }
  }
  __syncthreads();

  // ---- Stage D: per-pixel fusion + block reduction ----
  {
    int ty = tid >> 5, tx = tid & 31;   // 512 threads = full 16x32 tile
    int o = ty * PITCH + tx;
    float b[14];
#pragma unroll
    for (int f = 0; f < 14; ++f) b[f] = prod[f * PP + o];
    float muX = b[0];
    float muX2 = muX * muX;
    float sigX = b[1] - muX2;
    float num = 0.f, den = 0.f;
    float best_sig = -1e30f, best_cs = 0.f;
#pragma unroll
    for (int k = 0; k < 4; ++k) {
      float muY  = b[2 + k];
      float sigY = b[6 + k] - muY * muY;
      float sXY  = b[10 + k] - muX * muY;
      float cs = (2.f * sXY + 9e-4f) / (sigX + sigY + 9e-4f);
      if (sigY > best_sig) { best_sig = sigY; best_cs = cs; }  // first-max wins
      float dm = muY - 0.5f;
      float lL = expf(-dm * dm * 12.5f);          // /DENOM_L = *12.5
      float LY = (float)lG[k] * lL;
      num += LY * muY;
      den += LY;
    }
    float muYw = num / den;
    float l = (2.f * muX * muYw + 1e-4f) / (muX2 + muYw * muYw + 1e-4f);
    double v = (double)(l * best_cs);
    v = wave_red(v);
    int lane = tid & 63, wid = tid >> 6;
    if (lane == 0) qred[wid] = v;
    __syncthreads();
    if (tid == 0) {
      double t = 0.0;
#pragma unroll
      for (int i = 0; i < 8; ++i) t += qred[i];
      qpart[blockIdx.x] = t;
    }
  }
}

__global__ __launch_bounds__(512) void k3_final(const double* __restrict__ qpart,
                                                float* __restrict__ out) {
  double acc = 0.0;
  for (int i = threadIdx.x; i < 8192; i += 512) acc += qpart[i];
  acc = wave_red(acc);
  __shared__ double red[8];
  int lane = threadIdx.x & 63, wid = threadIdx.x >> 6;
  if (lane == 0) red[wid] = acc;
  __syncthreads();
  if (threadIdx.x == 0) out[0] = (float)((red[0]+red[1]+red[2]+red[3]+red[4]+red[5]+red[6]+red[7]) * (1.0 / 4194304.0));
}

extern "C" void kernel_launch(void* const* d_in, const int* in_sizes, int n_in,
                              void* d_out, int out_size, void* d_ws, size_t ws_size,
                              hipStream_t stream) {
  const float* X  = (const float*)d_in[0];
  const float* Ys = (const float*)d_in[1];
  char* ws = (char*)d_ws;
  float*  gwin   = (float*)(ws + 0);
  float*  gwin3  = (float*)(ws + 64);
  double* lG     = (double*)(ws + 128);
  double* lYpart = (double*)(ws + 256);
  double* qpart  = (double*)(ws + 16640);
  float* out = (float*)d_out;

  hipLaunchKernelGGL(k0_window, dim3(1), dim3(64), 0, stream, gwin, gwin3);
  hipLaunchKernelGGL(k1_lY, dim3(2048), dim3(256), 0, stream,
                     (const float4*)Ys, gwin, lYpart);
  hipLaunchKernelGGL(k2a_lG, dim3(1), dim3(256), 0, stream, lYpart, lG);
  hipLaunchKernelGGL(k2_main, dim3(8192), dim3(512), 0, stream, X, Ys, gwin, gwin3, lG, qpart);
  hipLaunchKernelGGL(k3_final, dim3(1), dim3(512), 0, stream, qpart, out);
}

// Round 3
// 170.978 us; speedup vs baseline: 2.0633x; 1.5603x over previous
//
#include <hip/hip_runtime.h>
#include <math.h>

#define HH 2048
#define WW 2048
#define PLANE 4194304        // HH*WW
#define TPITCH 44
#define TPP (26*TPITCH)      // 1144 floats per field plane

// ws layout (bytes):
// 0     : float gwin[11]
// 64    : float gwin3[11]
// 128   : double lG[4]
// 256   : double lYpart[4*528]   (16896 B)
// 17408 : double qpart[8192]     (65536 B)

__device__ inline double wave_red(double v) {
#pragma unroll
  for (int o = 32; o > 0; o >>= 1) v += __shfl_down(v, o, 64);
  return v;
}

__global__ void k0_window(float* gwin, float* gwin3) {
  if (threadIdx.x == 0) {
    double e[11], s = 0.0;
    double sig = 11.0 / 6.0;
    for (int i = 0; i < 11; ++i) {
      double x = (double)(i - 5);
      e[i] = exp(-(x * x) / (2.0 * sig * sig));
      s += e[i];
    }
    for (int i = 0; i < 11; ++i) {
      gwin[i]  = (float)(e[i] / s);
      gwin3[i] = (float)(e[i] / (3.0 * s));
    }
  }
}

// k1: lY partial sums.
// Blocks 0..2047: pure unweighted sum over a contiguous 6144-float4 chunk.
// Blocks 2048..2111: border correction sum of (wy*wx - 1)*v over border pixels.
__global__ __launch_bounds__(256) void k1_lY(const float* __restrict__ Ys,
                                             const float* __restrict__ gwin,
                                             double* __restrict__ lYpart) {
  int bid = blockIdx.x;
  int tid = threadIdx.x;
  double acc = 0.0;
  __shared__ float P[12];           // tap prefix sums (border blocks only)
  __shared__ double red[4];

  if (bid < 2048) {
    const float4* __restrict__ p = (const float4*)Ys;
    int base = bid * 6144 + tid;
#pragma unroll 1
    for (int gblk = 0; gblk < 3; ++gblk) {
      float ax = 0.f, ay = 0.f;
#pragma unroll
      for (int u = 0; u < 8; ++u) {
        float4 v = p[base + (gblk * 8 + u) * 256];
        ax += v.x + v.z;
        ay += v.y + v.w;
      }
      acc += (double)(ax + ay);
    }
  } else {
    int b = bid - 2048;             // 0..63
    int k = b >> 4, sub = b & 15;
    if (tid == 0) {
      float s = 0.f;
      for (int i = 0; i < 12; ++i) { P[i] = s; if (i < 11) s += gwin[i]; }
    }
    __syncthreads();
    const float4* __restrict__ Yk4 = (const float4*)(Ys + (size_t)k * 3 * PLANE);
    // covP(r) = coverage weight of input row/col r
    auto covP = [&](int r) -> float {
      if (r >= 5 && r <= 2042) return 1.0f;
      int dhi = r + 5; if (dhi > 10) dhi = 10;
      int dlo = r - 2042; if (dlo < 0) dlo = 0;
      return P[dhi + 1] - P[dlo];
    };
#pragma unroll 1
    for (int t = sub * 256 + tid; t < 39816; t += 4096) {
      int ch, row, g4;
      if (t < 15360) {              // full border rows: 3ch x 10 rows x 512 groups
        ch = t / 5120;
        int r = (t % 5120) / 512;
        g4 = t & 511;
        row = (r < 5) ? r : r + 2038;     // rows 0..4, 2043..2047
      } else {                      // interior rows, edge groups {0,1,510,511}
        int u = t - 15360;
        ch = u / 8152;
        int rem = u % 8152;
        row = 5 + (rem >> 2);
        int gi = rem & 3;
        g4 = (gi < 2) ? gi : 508 + gi;
      }
      float4 v = Yk4[ch * 1048576 + row * 512 + g4];
      float cy = covP(row);
      int x0 = g4 << 2;
      float w0 = cy * covP(x0)     - 1.0f;
      float w1 = cy * covP(x0 + 1) - 1.0f;
      float w2 = cy * covP(x0 + 2) - 1.0f;
      float w3 = cy * covP(x0 + 3) - 1.0f;
      acc += (double)(w0 * v.x + w1 * v.y + w2 * v.z + w3 * v.w);
    }
  }

  acc = wave_red(acc);
  int lane = tid & 63, wid = tid >> 6;
  if (bid >= 2048 && tid == 0) {} // (P barrier already passed)
  __syncthreads();
  if (lane == 0) red[wid] = acc;
  __syncthreads();
  if (tid == 0) {
    double tot = red[0] + red[1] + red[2] + red[3];
    if (bid < 2048) {
      int k = bid >> 9;
      lYpart[k * 528 + (bid & 511)] = tot;
    } else {
      int b = bid - 2048;
      lYpart[(b >> 4) * 528 + 512 + (b & 15)] = tot;
    }
  }
}

__global__ __launch_bounds__(256) void k2a_lG(const double* __restrict__ lYpart,
                                              double* __restrict__ lG) {
  __shared__ double red[4];
  for (int k = 0; k < 4; ++k) {
    const double* p = lYpart + k * 528;
    double v = p[threadIdx.x] + p[256 + threadIdx.x];
    if (threadIdx.x < 16) v += p[512 + threadIdx.x];
    v = wave_red(v);
    int lane = threadIdx.x & 63, wid = threadIdx.x >> 6;
    if (lane == 0) red[wid] = v;
    __syncthreads();
    if (threadIdx.x == 0) {
      double tot = red[0] + red[1] + red[2] + red[3];
      double lY = tot * (1.0 / 12582912.0);   // /(3*H*W) incl window /3
      double d = lY - 0.5;
      lG[k] = exp(-(d * d) / 0.08);
    }
    __syncthreads();
  }
}

// k2: 32x16 output tile. Halo columns [x0-6, x0+37] (width 44, pitch 44),
// halo rows [y0-5, y0+20] (26). 14 product fields, b128 LDS pipeline.
__global__ __launch_bounds__(512, 4) void k2_main(const float* __restrict__ X,
                                                  const float* __restrict__ Ys,
                                                  const float* __restrict__ gwin,
                                                  const float* __restrict__ gwin3,
                                                  const double* __restrict__ lG,
                                                  double* __restrict__ qpart) {
  __shared__ float4 lds4[(4 + 14 * TPP) / 4];   // 16020 floats = 64080 B
  __shared__ double qred[8];
  float* prod = (float*)lds4 + 4;               // 4-float guard below plane 0

  int bid = blockIdx.x;
  int wg = (bid & 7) * 1024 + (bid >> 3);       // XCD-compact swizzle
  int tX = wg & 63, tY = wg >> 6;
  int x0 = tX * 32, y0 = tY * 16;
  int tid = threadIdx.x;

  float g[11], g3[11];
#pragma unroll
  for (int i = 0; i < 11; ++i) { g[i] = gwin[i]; g3[i] = gwin3[i]; }

  // ---- Stage A: 26 rows x 11 float4-groups = 286 tasks ----
  if (tid < 286) {
    int row = tid / 11, g4 = tid - row * 11;
    int gy = y0 - 5 + row;
    int gx = x0 - 6 + g4 * 4;        // even, ≡2 mod 4
    bool rok = (unsigned)gy < (unsigned)HH;
    size_t rbase = (size_t)gy * WW;
    float v[15][4];
#pragma unroll
    for (int p = 0; p < 15; ++p) {
      const float* src = (p < 3) ? (X + (size_t)p * PLANE)
                                 : (Ys + (size_t)(p - 3) * PLANE);
#pragma unroll
      for (int h = 0; h < 2; ++h) {
        int xx = gx + 2 * h;
        float2 w2 = make_float2(0.f, 0.f);
        if (rok && (unsigned)xx < (unsigned)WW)
          w2 = *(const float2*)(src + rbase + xx);
        v[p][2 * h] = w2.x;
        v[p][2 * h + 1] = w2.y;
      }
    }
    int ob = row * TPITCH + g4 * 4;
    {
      float4 a, b2;
#pragma unroll
      for (int e = 0; e < 4; ++e) {
        float s0 = v[0][e], s1 = v[1][e], s2 = v[2][e];
        ((float*)&a)[e]  = s0 + s1 + s2;
        ((float*)&b2)[e] = s0 * s0 + s1 * s1 + s2 * s2;
      }
      *(float4*)(prod + 0 * TPP + ob) = a;
      *(float4*)(prod + 1 * TPP + ob) = b2;
#pragma unroll
      for (int k = 0; k < 4; ++k) {
        float4 sy, sy2, sxy;
#pragma unroll
        for (int e = 0; e < 4; ++e) {
          float ya = v[3 + 3 * k][e], yb = v[4 + 3 * k][e], yc = v[5 + 3 * k][e];
          ((float*)&sy)[e]  = ya + yb + yc;
          ((float*)&sy2)[e] = ya * ya + yb * yb + yc * yc;
          ((float*)&sxy)[e] = v[0][e] * ya + v[1][e] * yb + v[2][e] * yc;
        }
        *(float4*)(prod + (2 + k) * TPP + ob)  = sy;
        *(float4*)(prod + (6 + k) * TPP + ob)  = sy2;
        *(float4*)(prod + (10 + k) * TPP + ob) = sxy;
      }
    }
  }
  __syncthreads();

  // ---- Stage B: H-blur in place. 14 fields x 26 rows = 364 row tasks ----
  if (tid < 364) {
    int f = tid / 26, row = tid - f * 26;
    float* rp = prod + f * TPP + row * TPITCH;
    float w[44];
#pragma unroll
    for (int j = 0; j < 11; ++j) {
      float4 w4 = *(const float4*)(rp + 4 * j);
      w[4 * j] = w4.x; w[4 * j + 1] = w4.y; w[4 * j + 2] = w4.z; w[4 * j + 3] = w4.w;
    }
    // outputs at halo px 4..39 (px 4,5,38,39 are junk, never consumed)
#pragma unroll
    for (int gq = 0; gq < 9; ++gq) {
      float4 o4;
#pragma unroll
      for (int e = 0; e < 4; ++e) {
        int p = 4 * gq + e;          // out array idx, px = p+4
        float s = 0.f;
#pragma unroll
        for (int d = 0; d < 11; ++d) {
          int wi = p - 1 + d;        // px-5+d relative to halo
          if (wi < 0) wi = 0;        // junk-lane clamp (compile-time)
          if (wi > 43) wi = 43;
          s += g[d] * w[wi];
        }
        ((float*)&o4)[e] = s;
      }
      *(float4*)(rp + 4 + 4 * gq) = o4;
    }
  }
  __syncthreads();

  // ---- Stage C: V-blur, reg-buffered. 14 fields x 9 cgs x 2 halves = 252 ----
  float4 cacc[8];
  int cf = 0, ccg = 0, chalf = 0;
  bool cvalid = tid < 252;
  if (cvalid) {
    int t = tid;
    cf = t / 18;
    int r = t - cf * 18;
    ccg = 1 + (r >> 1);
    chalf = r & 1;
    const float* cp = prod + cf * TPP + (chalf * 8) * TPITCH + ccg * 4;
#pragma unroll
    for (int i = 0; i < 8; ++i) cacc[i] = make_float4(0.f, 0.f, 0.f, 0.f);
#pragma unroll
    for (int j = 0; j < 18; ++j) {
      float4 vv = *(const float4*)(cp + j * TPITCH);
#pragma unroll
      for (int r2 = 0; r2 < 8; ++r2) {
        int d = j - r2;
        if (d >= 0 && d < 11) {
          cacc[r2].x += g3[d] * vv.x;
          cacc[r2].y += g3[d] * vv.y;
          cacc[r2].z += g3[d] * vv.z;
          cacc[r2].w += g3[d] * vv.w;
        }
      }
    }
  }
  __syncthreads();
  if (cvalid) {
    float* cp = prod + cf * TPP + (chalf * 8) * TPITCH + ccg * 4;
#pragma unroll
    for (int r2 = 0; r2 < 8; ++r2)
      *(float4*)(cp + r2 * TPITCH) = cacc[r2];
  }
  __syncthreads();

  // ---- Stage D: per-pixel fusion + block reduction ----
  {
    int ty = tid >> 5, tx = tid & 31;
    int o = ty * TPITCH + 6 + tx;
    float b[14];
#pragma unroll
    for (int f = 0; f < 14; ++f) b[f] = prod[f * TPP + o];
    float muX = b[0];
    float muX2 = muX * muX;
    float sigX = b[1] - muX2;
    float num = 0.f, den = 0.f;
    float best_sig = -1e30f, best_cs = 0.f;
#pragma unroll
    for (int k = 0; k < 4; ++k) {
      float muY  = b[2 + k];
      float sigY = b[6 + k] - muY * muY;
      float sXY  = b[10 + k] - muX * muY;
      float cs = (2.f * sXY + 9e-4f) / (sigX + sigY + 9e-4f);
      if (sigY > best_sig) { best_sig = sigY; best_cs = cs; }
      float dm = muY - 0.5f;
      float lL = expf(-dm * dm * 12.5f);
      float LY = (float)lG[k] * lL;
      num += LY * muY;
      den += LY;
    }
    float muYw = num / den;
    float l = (2.f * muX * muYw + 1e-4f) / (muX2 + muYw * muYw + 1e-4f);
    double v = (double)(l * best_cs);
    v = wave_red(v);
    int lane = tid & 63, wid = tid >> 6;
    if (lane == 0) qred[wid] = v;
    __syncthreads();
    if (tid == 0) {
      double t = 0.0;
#pragma unroll
      for (int i = 0; i < 8; ++i) t += qred[i];
      qpart[blockIdx.x] = t;
    }
  }
}

__global__ __launch_bounds__(512) void k3_final(const double* __restrict__ qpart,
                                                float* __restrict__ out) {
  double acc = 0.0;
  for (int i = threadIdx.x; i < 8192; i += 512) acc += qpart[i];
  acc = wave_red(acc);
  __shared__ double red[8];
  int lane = threadIdx.x & 63, wid = threadIdx.x >> 6;
  if (lane == 0) red[wid] = acc;
  __syncthreads();
  if (threadIdx.x == 0)
    out[0] = (float)((red[0] + red[1] + red[2] + red[3] +
                      red[4] + red[5] + red[6] + red[7]) * (1.0 / 4194304.0));
}

extern "C" void kernel_launch(void* const* d_in, const int* in_sizes, int n_in,
                              void* d_out, int out_size, void* d_ws, size_t ws_size,
                              hipStream_t stream) {
  const float* X  = (const float*)d_in[0];
  const float* Ys = (const float*)d_in[1];
  char* ws = (char*)d_ws;
  float*  gwin   = (float*)(ws + 0);
  float*  gwin3  = (float*)(ws + 64);
  double* lG     = (double*)(ws + 128);
  double* lYpart = (double*)(ws + 256);
  double* qpart  = (double*)(ws + 17408);
  float* out = (float*)d_out;

  hipLaunchKernelGGL(k0_window, dim3(1), dim3(64), 0, stream, gwin, gwin3);
  hipLaunchKernelGGL(k1_lY, dim3(2112), dim3(256), 0, stream, Ys, gwin, lYpart);
  hipLaunchKernelGGL(k2a_lG, dim3(1), dim3(256), 0, stream, lYpart, lG);
  hipLaunchKernelGGL(k2_main, dim3(8192), dim3(512), 0, stream, X, Ys, gwin, gwin3, lG, qpart);
  hipLaunchKernelGGL(k3_final, dim3(1), dim3(512), 0, stream, qpart, out);
}